// Round 11
// baseline (519.830 us; speedup 1.0000x reference)
//
#include <hip/hip_runtime.h>

#define B_  8
#define P_  21
#define H_  32
#define W_  32

typedef float f32x4 __attribute__((ext_vector_type(4)));
typedef _Float16 f16x8 __attribute__((ext_vector_type(8)));

// ---------------------------------------------------------------- CSR build (parallel: zero+count+scan+fill)
struct CsrParams {
  const int*   row[4];
  const int*   col[4];
  const float* val[4];
  int*   cnt[4];
  int*   rowptr[4];
  int*   colsout[4];
  float* valsout[4];
  int    nnz[4];
  int    V[4];
};

__global__ void zero_cnt_kernel(int* p, int n) {
  int i = blockIdx.x * 256 + threadIdx.x;
  if (i < n) p[i] = 0;
}

__global__ void count_kernel(CsrParams p) {
  int l = blockIdx.y;
  int k = blockIdx.x * 256 + threadIdx.x;
  if (k < p.nnz[l]) atomicAdd(&p.cnt[l][p.row[l][k]], 1);
}

__global__ void scan_kernel(CsrParams p) {
  int l = blockIdx.x;
  int V = p.V[l];
  int* cnt = p.cnt[l];
  int* rp  = p.rowptr[l];
  int t = threadIdx.x;
  int chunk = V / 256;            // 4,8,16,32 — exact
  int base = t * chunk;
  int s = 0;
  for (int i = 0; i < chunk; ++i) s += cnt[base + i];
  __shared__ int sm[256];
  sm[t] = s;
  __syncthreads();
  for (int off = 1; off < 256; off <<= 1) {
    int v = (t >= off) ? sm[t - off] : 0;
    __syncthreads();
    sm[t] += v;
    __syncthreads();
  }
  int run = sm[t] - s;            // exclusive prefix
  for (int i = 0; i < chunk; ++i) {
    int c = cnt[base + i];
    rp[base + i]  = run;
    cnt[base + i] = run;          // becomes fill cursor
    run += c;
  }
  if (t == 255) rp[V] = run;
}

__global__ void fill_kernel(CsrParams p) {
  int l = blockIdx.y;
  int k = blockIdx.x * 256 + threadIdx.x;
  if (k < p.nnz[l]) {
    int r = p.row[l][k];
    int pos = atomicAdd(&p.cnt[l][r], 1);
    p.colsout[l][pos] = p.col[l][k];
    p.valsout[l][pos] = p.val[l][k];
  }
}

// ---------------------------------------------------------------- merged pool*dw table build
// Entry = (col | s<<16, val) packed in 8B. out[n] = sum_entries val*(wd[s] (.) x[col]).
struct Csr2Params {
  const int* sidx[4];      // [V][9]
  const int* rp[4];        // pool CSR rowptr
  const int* co[4];        // pool CSR cols
  const float* va[4];      // pool CSR vals
  int* kcnt[4];            // per-row merged entry count
  int* rp2[4];             // merged rowptr
  long long* tab[4];       // merged entry table
  int V[4];
};

__global__ void kcnt_kernel(Csr2Params p) {
  int l = blockIdx.y;
  int n = blockIdx.x * 256 + threadIdx.x;
  if (n >= p.V[l]) return;
  const int* si = p.sidx[l] + n * 9;
  const int* rp = p.rp[l];
  int s = 0;
  #pragma unroll
  for (int t = 0; t < 9; ++t) {
    int r = si[t];
    s += rp[r + 1] - rp[r];
  }
  p.kcnt[l][n] = s;
}

__global__ void scan2_kernel(Csr2Params p) {
  int l = blockIdx.x;
  int V = p.V[l];
  int* cnt = p.kcnt[l];
  int* rp2 = p.rp2[l];
  int t = threadIdx.x;
  int chunk = V / 256;
  int base = t * chunk;
  int s = 0;
  for (int i = 0; i < chunk; ++i) s += cnt[base + i];
  __shared__ int sm[256];
  sm[t] = s;
  __syncthreads();
  for (int off = 1; off < 256; off <<= 1) {
    int v = (t >= off) ? sm[t - off] : 0;
    __syncthreads();
    sm[t] += v;
    __syncthreads();
  }
  int run = sm[t] - s;
  for (int i = 0; i < chunk; ++i) {
    int c = cnt[base + i];
    rp2[base + i] = run;
    run += c;
  }
  if (t == 255) rp2[V] = run;
}

__global__ void fill2_kernel(Csr2Params p) {
  int l = blockIdx.y;
  int id = blockIdx.x * 256 + threadIdx.x;
  int V = p.V[l];
  if (id >= 9 * V) return;
  int n = id / 9;
  int s = id - n * 9;
  const int* si = p.sidx[l] + n * 9;
  const int* rp = p.rp[l];
  int off = p.rp2[l][n];
  for (int t = 0; t < s; ++t) {
    int r = si[t];
    off += rp[r + 1] - rp[r];
  }
  int r = si[s];
  int j0 = rp[r], j1 = rp[r + 1];
  const int* co = p.co[l];
  const float* va = p.va[l];
  long long* tab = p.tab[l];
  for (int j = j0; j < j1; ++j) {
    unsigned int lo = (unsigned int)(co[j] | (s << 16));
    unsigned int hi = __float_as_uint(va[j]);
    tab[off++] = (long long)(((unsigned long long)hi << 32) | lo);
  }
}

// ---------------------------------------------------------------- sampling
__global__ void sample_kernel(const float* __restrict__ uv,
                              const float* __restrict__ feat,
                              float* __restrict__ xs) {
  int bp = blockIdx.x;
  int b  = bp / P_;
  float u0 = uv[bp * 2 + 0], u1 = uv[bp * 2 + 1];
  float gx = fminf(fmaxf((u0 - 0.5f) * 2.0f, -1.0f), 1.0f);
  float gy = fminf(fmaxf((u1 - 0.5f) * 2.0f, -1.0f), 1.0f);
  float fx = (gx + 1.0f) * 0.5f * (W_ - 1);
  float fy = (gy + 1.0f) * 0.5f * (H_ - 1);
  float x0f = floorf(fx), y0f = floorf(fy);
  float wx = fx - x0f, wy = fy - y0f;
  int x0 = (int)x0f, y0 = (int)y0f;
  int x0i = min(max(x0, 0), W_ - 1), x1i = min(max(x0 + 1, 0), W_ - 1);
  int y0i = min(max(y0, 0), H_ - 1), y1i = min(max(y0 + 1, 0), H_ - 1);
  float w00 = (1.f - wy) * (1.f - wx), w01 = (1.f - wy) * wx;
  float w10 = wy * (1.f - wx),        w11 = wy * wx;
  for (int c = threadIdx.x; c < 512; c += blockDim.x) {
    const float* fb = feat + ((size_t)(b * 512 + c)) * (H_ * W_);
    float v = fb[y0i * W_ + x0i] * w00 + fb[y0i * W_ + x1i] * w01 +
              fb[y1i * W_ + x0i] * w10 + fb[y1i * W_ + x1i] * w11;
    xs[(size_t)bp * 512 + c] = v;
  }
}

__global__ void upsample_kernel(const float* __restrict__ up,
                                const float* __restrict__ xs,
                                float* __restrict__ xu) {
  int v = blockIdx.x, b = blockIdx.y;
  int c4 = threadIdx.x << 2;
  float4 acc = make_float4(0.f, 0.f, 0.f, 0.f);
  for (int p = 0; p < P_; ++p) {
    float u = up[v * P_ + p];
    const float4 xv = *(const float4*)&xs[((size_t)(b * P_ + p)) * 512 + c4];
    acc.x = fmaf(u, xv.x, acc.x);
    acc.y = fmaf(u, xv.y, acc.y);
    acc.z = fmaf(u, xv.z, acc.z);
    acc.w = fmaf(u, xv.w, acc.w);
  }
  *(float4*)&xu[((size_t)(b * 512 + v)) * 512 + c4] = acc;
}

// ---------------------------------------------------------------- fused pool*dw via merged table + f16x2 split
// batch-affine; per thread: 8 channels, one output row, ~27 independent gathers
// from the stage-input x (1-2MB/batch -> L2-resident per XCD).
__global__ __launch_bounds__(256) void dw27_kernel(
    const float* __restrict__ x,         // [B][Vin][Cin]
    const long long* __restrict__ tab,   // merged entries
    const int* __restrict__ rp2,
    const float* __restrict__ wd,        // [9][Cin]
    _Float16* __restrict__ a0o,
    _Float16* __restrict__ a1o,
    int Vout, int Vin, int Cin) {
  const int lpr    = Cin >> 3;
  const int lshift = 31 - __clz(lpr);
  const int rpb    = 256 >> lshift;
  const int lr = threadIdx.x >> lshift;
  const int lc = threadIdx.x & (lpr - 1);
  const int b  = blockIdx.x & 7;            // XCD-affine batch
  const int n  = (blockIdx.x >> 3) * rpb + lr;
  const int c8 = lc << 3;
  const float* xb  = x + (size_t)b * Vin * Cin + c8;
  const float* wdc = wd + c8;

  int e0 = rp2[n], e1 = rp2[n + 1];
  float4 a0 = make_float4(0.f, 0.f, 0.f, 0.f);
  float4 a1 = make_float4(0.f, 0.f, 0.f, 0.f);

  int e = e0;
  for (; e + 3 <= e1; e += 3) {
    long long v0 = __builtin_nontemporal_load(&tab[e]);
    long long v1 = __builtin_nontemporal_load(&tab[e + 1]);
    long long v2 = __builtin_nontemporal_load(&tab[e + 2]);
    int col0 = (int)((unsigned long long)v0 & 0xFFFF);
    int col1 = (int)((unsigned long long)v1 & 0xFFFF);
    int col2 = (int)((unsigned long long)v2 & 0xFFFF);
    int s0 = (int)(((unsigned long long)v0 >> 16) & 0xFF);
    int s1 = (int)(((unsigned long long)v1 >> 16) & 0xFF);
    int s2 = (int)(((unsigned long long)v2 >> 16) & 0xFF);
    float val0 = __uint_as_float((unsigned int)((unsigned long long)v0 >> 32));
    float val1 = __uint_as_float((unsigned int)((unsigned long long)v1 >> 32));
    float val2 = __uint_as_float((unsigned int)((unsigned long long)v2 >> 32));
    const float* xr0 = xb + (size_t)col0 * Cin;
    const float* xr1 = xb + (size_t)col1 * Cin;
    const float* xr2 = xb + (size_t)col2 * Cin;
    float4 p00 = *(const float4*)xr0, p01 = *(const float4*)(xr0 + 4);
    float4 p10 = *(const float4*)xr1, p11 = *(const float4*)(xr1 + 4);
    float4 p20 = *(const float4*)xr2, p21 = *(const float4*)(xr2 + 4);
    const float* wr0 = wdc + s0 * Cin;
    const float* wr1 = wdc + s1 * Cin;
    const float* wr2 = wdc + s2 * Cin;
    float4 w00 = *(const float4*)wr0, w01 = *(const float4*)(wr0 + 4);
    float4 w10 = *(const float4*)wr1, w11 = *(const float4*)(wr1 + 4);
    float4 w20 = *(const float4*)wr2, w21 = *(const float4*)(wr2 + 4);
    a0.x = fmaf(val0 * w00.x, p00.x, a0.x); a0.y = fmaf(val0 * w00.y, p00.y, a0.y);
    a0.z = fmaf(val0 * w00.z, p00.z, a0.z); a0.w = fmaf(val0 * w00.w, p00.w, a0.w);
    a1.x = fmaf(val0 * w01.x, p01.x, a1.x); a1.y = fmaf(val0 * w01.y, p01.y, a1.y);
    a1.z = fmaf(val0 * w01.z, p01.z, a1.z); a1.w = fmaf(val0 * w01.w, p01.w, a1.w);
    a0.x = fmaf(val1 * w10.x, p10.x, a0.x); a0.y = fmaf(val1 * w10.y, p10.y, a0.y);
    a0.z = fmaf(val1 * w10.z, p10.z, a0.z); a0.w = fmaf(val1 * w10.w, p10.w, a0.w);
    a1.x = fmaf(val1 * w11.x, p11.x, a1.x); a1.y = fmaf(val1 * w11.y, p11.y, a1.y);
    a1.z = fmaf(val1 * w11.z, p11.z, a1.z); a1.w = fmaf(val1 * w11.w, p11.w, a1.w);
    a0.x = fmaf(val2 * w20.x, p20.x, a0.x); a0.y = fmaf(val2 * w20.y, p20.y, a0.y);
    a0.z = fmaf(val2 * w20.z, p20.z, a0.z); a0.w = fmaf(val2 * w20.w, p20.w, a0.w);
    a1.x = fmaf(val2 * w21.x, p21.x, a1.x); a1.y = fmaf(val2 * w21.y, p21.y, a1.y);
    a1.z = fmaf(val2 * w21.z, p21.z, a1.z); a1.w = fmaf(val2 * w21.w, p21.w, a1.w);
  }
  for (; e < e1; ++e) {
    long long v0 = __builtin_nontemporal_load(&tab[e]);
    int col0 = (int)((unsigned long long)v0 & 0xFFFF);
    int s0 = (int)(((unsigned long long)v0 >> 16) & 0xFF);
    float val0 = __uint_as_float((unsigned int)((unsigned long long)v0 >> 32));
    const float* xr0 = xb + (size_t)col0 * Cin;
    float4 p00 = *(const float4*)xr0, p01 = *(const float4*)(xr0 + 4);
    const float* wr0 = wdc + s0 * Cin;
    float4 w00 = *(const float4*)wr0, w01 = *(const float4*)(wr0 + 4);
    a0.x = fmaf(val0 * w00.x, p00.x, a0.x); a0.y = fmaf(val0 * w00.y, p00.y, a0.y);
    a0.z = fmaf(val0 * w00.z, p00.z, a0.z); a0.w = fmaf(val0 * w00.w, p00.w, a0.w);
    a1.x = fmaf(val0 * w01.x, p01.x, a1.x); a1.y = fmaf(val0 * w01.y, p01.y, a1.y);
    a1.z = fmaf(val0 * w01.z, p01.z, a1.z); a1.w = fmaf(val0 * w01.w, p01.w, a1.w);
  }

  size_t m = (size_t)b * Vout + n;
  float v[8] = {a0.x, a0.y, a0.z, a0.w, a1.x, a1.y, a1.z, a1.w};
  f16x8 hi, lo;
  #pragma unroll
  for (int i = 0; i < 8; ++i) {
    _Float16 h0 = (_Float16)v[i];
    float r = (v[i] - (float)h0) * 2048.0f;   // exact pow2; lo-plane stays normal
    hi[i] = h0;
    lo[i] = (_Float16)r;
  }
  *(f16x8*)&a0o[m * Cin + c8] = hi;
  *(f16x8*)&a1o[m * Cin + c8] = lo;
}

// ---------------------------------------------------------------- B split, all 4 stages in one launch
struct BsplitParams {
  const float* wp[4];
  int K[4], N[4], off[4];
  _Float16* b0;
  _Float16* b1;
};

__global__ void bsplit_all_kernel(BsplitParams p) {
  int idx = blockIdx.x * 256 + threadIdx.x;
  #pragma unroll
  for (int t = 0; t < 4; ++t) {
    int sz = p.N[t] * p.K[t];
    if (idx < sz) {
      int n = idx / p.K[t], k = idx - n * p.K[t];
      float v = p.wp[t][(size_t)k * p.N[t] + n];
      _Float16 h0 = (_Float16)v;
      float r = (v - (float)h0) * 2048.0f;
      p.b0[p.off[t] + idx] = h0;
      p.b1[p.off[t] + idx] = (_Float16)r;
      return;
    }
    idx -= sz;
  }
}

// ---------------------------------------------------------------- f16x2-split MFMA GEMM + bias + relu (batch-affine)
// BM=128, BN=64, BK=64; 2x2 waves, wave tile 64x32, mfma 16x16x32.
__global__ __launch_bounds__(256) void gemm_f16x2(
    const _Float16* __restrict__ A0, const _Float16* __restrict__ A1,
    const _Float16* __restrict__ Bt0, const _Float16* __restrict__ Bt1,
    const float* __restrict__ bias, float* __restrict__ C,
    int M, int N, int K) {
  constexpr int RP = 72;
  __shared__ _Float16 As[2][128][RP];
  __shared__ _Float16 Bs[2][64][RP];
  const int tid = threadIdx.x;
  const int bx = blockIdx.x;
  const int xr_ = (bx & 7) * (gridDim.x >> 3) + (bx >> 3);   // batch-affine remap
  const int m0 = xr_ * 128, n0 = blockIdx.y * 64;
  const int wid = tid >> 6, lane = tid & 63;
  const int wr = wid >> 1, wc = wid & 1;
  const int lo = lane & 15, hi = lane >> 4;

  f32x4 accM[4][2], accC[4][2];
  #pragma unroll
  for (int mi = 0; mi < 4; ++mi)
    #pragma unroll
    for (int nj = 0; nj < 2; ++nj) {
      accM[mi][nj] = (f32x4){0.f, 0.f, 0.f, 0.f};
      accC[mi][nj] = (f32x4){0.f, 0.f, 0.f, 0.f};
    }

  const _Float16* gA[2] = {A0, A1};
  const _Float16* gB[2] = {Bt0, Bt1};

  for (int k0 = 0; k0 < K; k0 += 64) {
    #pragma unroll
    for (int p = 0; p < 2; ++p) {
      #pragma unroll
      for (int i = 0; i < 4; ++i) {
        int c = tid + 256 * i;
        int r = c >> 3, k8 = (c & 7) << 3;
        uint4 v = *(const uint4*)(gA[p] + (size_t)(m0 + r) * K + k0 + k8);
        *(uint4*)&As[p][r][k8] = v;
      }
      #pragma unroll
      for (int i = 0; i < 2; ++i) {
        int c = tid + 256 * i;
        int r = c >> 3, k8 = (c & 7) << 3;
        uint4 v = *(const uint4*)(gB[p] + (size_t)(n0 + r) * K + k0 + k8);
        *(uint4*)&Bs[p][r][k8] = v;
      }
    }
    __syncthreads();
    #pragma unroll
    for (int s = 0; s < 2; ++s) {
      const int kk = s * 32 + hi * 8;
      f16x8 af[4][2], bf[2][2];
      #pragma unroll
      for (int mi = 0; mi < 4; ++mi) {
        af[mi][0] = *(const f16x8*)&As[0][wr * 64 + mi * 16 + lo][kk];
        af[mi][1] = *(const f16x8*)&As[1][wr * 64 + mi * 16 + lo][kk];
      }
      #pragma unroll
      for (int nj = 0; nj < 2; ++nj) {
        bf[nj][0] = *(const f16x8*)&Bs[0][wc * 32 + nj * 16 + lo][kk];
        bf[nj][1] = *(const f16x8*)&Bs[1][wc * 32 + nj * 16 + lo][kk];
      }
      #pragma unroll
      for (int mi = 0; mi < 4; ++mi)
        #pragma unroll
        for (int nj = 0; nj < 2; ++nj) {
          accM[mi][nj] = __builtin_amdgcn_mfma_f32_16x16x32_f16(
              af[mi][0], bf[nj][0], accM[mi][nj], 0, 0, 0);
          accC[mi][nj] = __builtin_amdgcn_mfma_f32_16x16x32_f16(
              af[mi][0], bf[nj][1], accC[mi][nj], 0, 0, 0);
          accC[mi][nj] = __builtin_amdgcn_mfma_f32_16x16x32_f16(
              af[mi][1], bf[nj][0], accC[mi][nj], 0, 0, 0);
        }
    }
    __syncthreads();
  }

  const float INV = 1.0f / 2048.0f;
  #pragma unroll
  for (int mi = 0; mi < 4; ++mi)
    #pragma unroll
    for (int nj = 0; nj < 2; ++nj) {
      int col = n0 + wc * 32 + nj * 16 + lo;
      float bv = bias[col];
      #pragma unroll
      for (int r = 0; r < 4; ++r) {
        int row = m0 + wr * 64 + mi * 16 + hi * 4 + r;
        float v = accM[mi][nj][r] + accC[mi][nj][r] * INV + bv;
        v = fmaxf(v, 0.f);
        C[(size_t)row * N + col] = v;
      }
    }
}

// ---------------------------------------------------------------- fused head: dw (Cin=64, lane=channel) + 64x3 proj
__global__ __launch_bounds__(256) void head_fused_kernel(
    const float* __restrict__ x,      // [8][8192][64]
    const int* __restrict__ sidx,     // [8192][9]
    const float* __restrict__ wdh,    // [9][64]
    const float* __restrict__ wph,    // [64][3]
    const float* __restrict__ bh,
    float* __restrict__ out) {        // [8][8192][3]
  const int bid  = blockIdx.x;
  const int b    = bid & 7;           // XCD-affine batch
  const int wid  = threadIdx.x >> 6;
  const int lane = threadIdx.x & 63;
  const int n    = (bid >> 3) * 4 + wid;
  const float* xb = x + (size_t)b * 8192 * 64 + lane;

  int idx[9];
  #pragma unroll
  for (int s = 0; s < 9; ++s) idx[s] = sidx[n * 9 + s];

  float acc = 0.f;
  #pragma unroll
  for (int s = 0; s < 9; ++s)
    acc = fmaf(wdh[s * 64 + lane], xb[(size_t)idx[s] * 64], acc);

  float a0 = acc * wph[lane * 3 + 0];
  float a1 = acc * wph[lane * 3 + 1];
  float a2 = acc * wph[lane * 3 + 2];
  for (int off = 32; off > 0; off >>= 1) {
    a0 += __shfl_down(a0, off);
    a1 += __shfl_down(a1, off);
    a2 += __shfl_down(a2, off);
  }
  if (lane == 0) {
    size_t row = (size_t)b * 8192 + n;
    out[row * 3 + 0] = a0 + bh[0];
    out[row * 3 + 1] = a1 + bh[1];
    out[row * 3 + 2] = a2 + bh[2];
  }
}

// ---------------------------------------------------------------- launch
extern "C" void kernel_launch(void* const* d_in, const int* in_sizes, int n_in,
                              void* d_out, int out_size, void* d_ws, size_t ws_size,
                              hipStream_t stream) {
  const float* uv   = (const float*)d_in[0];
  const float* feat = (const float*)d_in[1];
  const float* up   = (const float*)d_in[2];
  const int* sArr[4] = {(const int*)d_in[3], (const int*)d_in[4],
                        (const int*)d_in[5], (const int*)d_in[6]};

  // workspace layout
  const size_t SLAB = 8ull * 2048 * 512;            // 8,388,608 elements
  float* Wf = (float*)d_ws;
  float* S0 = Wf;                                   // fp32 slab (x / gemm out); live < 4.2M floats
  float* S1 = Wf + SLAB;                            // now: merged tables region
  _Float16* A0 = (_Float16*)(S1 + SLAB);            // dw hi plane
  _Float16* A1 = A0 + SLAB;                         // dw lo plane
  _Float16* Bt0all = (_Float16*)(S0 + 4500000);     // dead upper part of S0
  _Float16* Bt1all = Bt0all + 434176;
  float* xs = (float*)(A1 + SLAB);                  // B*P*512 floats
  int* ib = (int*)(xs + (size_t)B_ * P_ * 512);

  int Vt[4] = {1024, 2048, 4096, 8192};
  int NZ[4] = {3072, 6144, 12288, 24576};
  int* cnt[4]; int* rp[4]; int* co[4]; float* va[4];
  int* kcnt[4]; int* rp2[4];
  {
    int* pc = ib;
    for (int t = 0; t < 4; ++t) { cnt[t] = pc; pc += Vt[t]; }          // 15360 ints
    for (int t = 0; t < 4; ++t) { rp[t] = pc; pc += Vt[t] + 1; }
    for (int t = 0; t < 4; ++t) { co[t] = pc; pc += NZ[t]; }
    float* pv = (float*)pc;
    for (int t = 0; t < 4; ++t) { va[t] = pv; pv += NZ[t]; }
    pc = (int*)pv;
    for (int t = 0; t < 4; ++t) { kcnt[t] = pc; pc += Vt[t]; }
    for (int t = 0; t < 4; ++t) { rp2[t] = pc; pc += Vt[t] + 1; }
  }
  // merged tables in S1 region (48 entries/row worst-case; expected 27)
  long long* tab[4];
  {
    long long* pt = (long long*)S1;
    for (int t = 0; t < 4; ++t) { tab[t] = pt; pt += 48ull * Vt[t]; }  // 737280 * 8B
  }

  CsrParams cp;
  for (int t = 0; t < 4; ++t) {
    int i = 3 - t;
    cp.row[t] = (const int*)d_in[7 + 3 * i];
    cp.col[t] = (const int*)d_in[8 + 3 * i];
    cp.val[t] = (const float*)d_in[9 + 3 * i];
    cp.cnt[t] = cnt[t]; cp.rowptr[t] = rp[t];
    cp.colsout[t] = co[t]; cp.valsout[t] = va[t];
    cp.nnz[t] = NZ[t]; cp.V[t] = Vt[t];
  }

  Csr2Params c2;
  for (int t = 0; t < 4; ++t) {
    c2.sidx[t] = sArr[3 - t];     // stage t uses sidx level 3-t (matches Vt[t])
    c2.rp[t] = rp[t]; c2.co[t] = co[t]; c2.va[t] = va[t];
    c2.kcnt[t] = kcnt[t]; c2.rp2[t] = rp2[t]; c2.tab[t] = tab[t];
    c2.V[t] = Vt[t];
  }

  // CSR build + merged-table build
  zero_cnt_kernel<<<60, 256, 0, stream>>>(ib, 15360);
  count_kernel<<<dim3(96, 4), 256, 0, stream>>>(cp);
  scan_kernel<<<4, 256, 0, stream>>>(cp);
  fill_kernel<<<dim3(96, 4), 256, 0, stream>>>(cp);
  kcnt_kernel<<<dim3(32, 4), 256, 0, stream>>>(c2);
  scan2_kernel<<<4, 256, 0, stream>>>(c2);
  fill2_kernel<<<dim3(288, 4), 256, 0, stream>>>(c2);

  sample_kernel<<<B_ * P_, 256, 0, stream>>>(uv, feat, xs);
  upsample_kernel<<<dim3(512, B_), 128, 0, stream>>>(up, xs, S0);

  struct Stg { int Vin, Vout, Cin, Cout; const int* s; const float *wd, *wp, *bias; };
  Stg st[4] = {
    {512, 1024, 512, 512, sArr[3], (const float*)d_in[19], (const float*)d_in[20], (const float*)d_in[21]},
    {1024, 2048, 512, 256, sArr[2], (const float*)d_in[22], (const float*)d_in[23], (const float*)d_in[24]},
    {2048, 4096, 256, 128, sArr[1], (const float*)d_in[25], (const float*)d_in[26], (const float*)d_in[27]},
    {4096, 8192, 128, 64, sArr[0], (const float*)d_in[28], (const float*)d_in[29], (const float*)d_in[30]},
  };

  // all 4 B-splits in one launch
  BsplitParams bp;
  int boff = 0;
  for (int t = 0; t < 4; ++t) {
    bp.wp[t] = st[t].wp;
    bp.K[t] = st[t].Cin; bp.N[t] = st[t].Cout;
    bp.off[t] = boff;
    boff += st[t].Cin * st[t].Cout;           // 434176 total
  }
  bp.b0 = Bt0all; bp.b1 = Bt1all;
  bsplit_all_kernel<<<(boff + 255) / 256, 256, 0, stream>>>(bp);

  for (int t = 0; t < 4; ++t) {
    int rpb = 2048 / st[t].Cin;               // rows/block at 8 ch/thread
    // fused pool*dw via merged entry table (single gather pass from L2-resident x)
    dw27_kernel<<<8 * (st[t].Vout / rpb), 256, 0, stream>>>(
        S0, tab[t], rp2[t], st[t].wd, A0, A1,
        st[t].Vout, st[t].Vin, st[t].Cin);
    int M = B_ * st[t].Vout;
    gemm_f16x2<<<dim3(M / 128, st[t].Cout / 64), 256, 0, stream>>>(
        A0, A1, Bt0all + bp.off[t], Bt1all + bp.off[t],
        st[t].bias, S0, M, st[t].Cout, st[t].Cin);
  }

  // fused head: dw (K=64) + 64x3 projection, one launch
  head_fused_kernel<<<8 * (8192 / 4), 256, 0, stream>>>(
      S0, sArr[0], (const float*)d_in[31], (const float*)d_in[32],
      (const float*)d_in[33], (float*)d_out);
}

// Round 12
// 278.572 us; speedup vs baseline: 1.8661x; 1.8661x over previous
//
#include <hip/hip_runtime.h>

#define B_  8
#define P_  21
#define H_  32
#define W_  32

typedef float f32x4 __attribute__((ext_vector_type(4)));
typedef _Float16 f16x8 __attribute__((ext_vector_type(8)));

// ---------------------------------------------------------------- CSR build (parallel: zero+count+scan+fill)
struct CsrParams {
  const int*   row[4];
  const int*   col[4];
  const float* val[4];
  int*   cnt[4];
  int*   rowptr[4];
  int*   colsout[4];
  float* valsout[4];
  int    nnz[4];
  int    V[4];
};

__global__ void zero_cnt_kernel(int* p, int n) {
  int i = blockIdx.x * 256 + threadIdx.x;
  if (i < n) p[i] = 0;
}

__global__ void count_kernel(CsrParams p) {
  int l = blockIdx.y;
  int k = blockIdx.x * 256 + threadIdx.x;
  if (k < p.nnz[l]) atomicAdd(&p.cnt[l][p.row[l][k]], 1);
}

__global__ void scan_kernel(CsrParams p) {
  int l = blockIdx.x;
  int V = p.V[l];
  int* cnt = p.cnt[l];
  int* rp  = p.rowptr[l];
  int t = threadIdx.x;
  int chunk = V / 256;            // 4,8,16,32 — exact
  int base = t * chunk;
  int s = 0;
  for (int i = 0; i < chunk; ++i) s += cnt[base + i];
  __shared__ int sm[256];
  sm[t] = s;
  __syncthreads();
  for (int off = 1; off < 256; off <<= 1) {
    int v = (t >= off) ? sm[t - off] : 0;
    __syncthreads();
    sm[t] += v;
    __syncthreads();
  }
  int run = sm[t] - s;            // exclusive prefix
  for (int i = 0; i < chunk; ++i) {
    int c = cnt[base + i];
    rp[base + i]  = run;
    cnt[base + i] = run;          // becomes fill cursor
    run += c;
  }
  if (t == 255) rp[V] = run;
}

__global__ void fill_kernel(CsrParams p) {
  int l = blockIdx.y;
  int k = blockIdx.x * 256 + threadIdx.x;
  if (k < p.nnz[l]) {
    int r = p.row[l][k];
    int pos = atomicAdd(&p.cnt[l][r], 1);
    p.colsout[l][pos] = p.col[l][k];
    p.valsout[l][pos] = p.val[l][k];
  }
}

// ---------------------------------------------------------------- sampling
__global__ void sample_kernel(const float* __restrict__ uv,
                              const float* __restrict__ feat,
                              float* __restrict__ xs) {
  int bp = blockIdx.x;
  int b  = bp / P_;
  float u0 = uv[bp * 2 + 0], u1 = uv[bp * 2 + 1];
  float gx = fminf(fmaxf((u0 - 0.5f) * 2.0f, -1.0f), 1.0f);
  float gy = fminf(fmaxf((u1 - 0.5f) * 2.0f, -1.0f), 1.0f);
  float fx = (gx + 1.0f) * 0.5f * (W_ - 1);
  float fy = (gy + 1.0f) * 0.5f * (H_ - 1);
  float x0f = floorf(fx), y0f = floorf(fy);
  float wx = fx - x0f, wy = fy - y0f;
  int x0 = (int)x0f, y0 = (int)y0f;
  int x0i = min(max(x0, 0), W_ - 1), x1i = min(max(x0 + 1, 0), W_ - 1);
  int y0i = min(max(y0, 0), H_ - 1), y1i = min(max(y0 + 1, 0), H_ - 1);
  float w00 = (1.f - wy) * (1.f - wx), w01 = (1.f - wy) * wx;
  float w10 = wy * (1.f - wx),        w11 = wy * wx;
  for (int c = threadIdx.x; c < 512; c += blockDim.x) {
    const float* fb = feat + ((size_t)(b * 512 + c)) * (H_ * W_);
    float v = fb[y0i * W_ + x0i] * w00 + fb[y0i * W_ + x1i] * w01 +
              fb[y1i * W_ + x0i] * w10 + fb[y1i * W_ + x1i] * w11;
    xs[(size_t)bp * 512 + c] = v;
  }
}

__global__ void upsample_kernel(const float* __restrict__ up,
                                const float* __restrict__ xs,
                                float* __restrict__ xu) {
  int v = blockIdx.x, b = blockIdx.y;
  int c4 = threadIdx.x << 2;
  float4 acc = make_float4(0.f, 0.f, 0.f, 0.f);
  for (int p = 0; p < P_; ++p) {
    float u = up[v * P_ + p];
    const float4 xv = *(const float4*)&xs[((size_t)(b * P_ + p)) * 512 + c4];
    acc.x = fmaf(u, xv.x, acc.x);
    acc.y = fmaf(u, xv.y, acc.y);
    acc.z = fmaf(u, xv.z, acc.z);
    acc.w = fmaf(u, xv.w, acc.w);
  }
  *(float4*)&xu[((size_t)(b * 512 + v)) * 512 + c4] = acc;
}

// ---------------------------------------------------------------- pool (CSR gather, batch-affine, 8ch/thread)
// First 4 (col,val) pairs prefetched into registers -> 4 independent 32B
// gathers (breaks the cols[j]->x[col] serial chain); rare tail loop for cnt>4.
// Padding terms use val=0 AFTER the real entries: summation order preserved.
__global__ __launch_bounds__(256) void pool_kernel(
    const float* __restrict__ x,
    const int* __restrict__ rowptr,
    const int* __restrict__ cols,
    const float* __restrict__ vals,
    float* __restrict__ out,
    int Vout, int Vin, int Cin) {
  const int lpr    = Cin >> 3;
  const int lshift = 31 - __clz(lpr);
  const int rpb    = 256 >> lshift;
  const int lr = threadIdx.x >> lshift;
  const int lc = threadIdx.x & (lpr - 1);
  const int b  = blockIdx.x & 7;            // XCD-affine batch
  const int n  = (blockIdx.x >> 3) * rpb + lr;
  const int c8 = lc << 3;
  const float* xb = x + (size_t)b * Vin * Cin + c8;
  int j0 = rowptr[n], j1 = rowptr[n + 1];
  int cnt = j1 - j0;
  float4 a0 = make_float4(0.f, 0.f, 0.f, 0.f);
  float4 a1 = make_float4(0.f, 0.f, 0.f, 0.f);
  if (cnt > 0) {
    int   cc[4];
    float vv[4];
    #pragma unroll
    for (int k = 0; k < 4; ++k) {
      int jj = j0 + ((k < cnt) ? k : 0);    // in-bounds (cnt>0)
      cc[k] = cols[jj];
      vv[k] = (k < cnt) ? vals[jj] : 0.f;
    }
    #pragma unroll
    for (int k = 0; k < 4; ++k) {
      const float* xr = xb + (size_t)cc[k] * Cin;
      float4 x0 = *(const float4*)xr;
      float4 x1 = *(const float4*)(xr + 4);
      float v = vv[k];
      a0.x = fmaf(v, x0.x, a0.x); a0.y = fmaf(v, x0.y, a0.y);
      a0.z = fmaf(v, x0.z, a0.z); a0.w = fmaf(v, x0.w, a0.w);
      a1.x = fmaf(v, x1.x, a1.x); a1.y = fmaf(v, x1.y, a1.y);
      a1.z = fmaf(v, x1.z, a1.z); a1.w = fmaf(v, x1.w, a1.w);
    }
    for (int j = j0 + 4; j < j1; ++j) {     // rare tail (cnt>4)
      float v = vals[j];
      const float* xr = xb + (size_t)cols[j] * Cin;
      float4 x0 = *(const float4*)xr;
      float4 x1 = *(const float4*)(xr + 4);
      a0.x = fmaf(v, x0.x, a0.x); a0.y = fmaf(v, x0.y, a0.y);
      a0.z = fmaf(v, x0.z, a0.z); a0.w = fmaf(v, x0.w, a0.w);
      a1.x = fmaf(v, x1.x, a1.x); a1.y = fmaf(v, x1.y, a1.y);
      a1.z = fmaf(v, x1.z, a1.z); a1.w = fmaf(v, x1.w, a1.w);
    }
  }
  float* op = &out[((size_t)b * Vout + n) * Cin + c8];
  *(float4*)op = a0;
  *(float4*)(op + 4) = a1;
}

// ---------------------------------------------------------------- dw gather + f16x2 split (batch-affine, 8ch/thread)
__global__ __launch_bounds__(256) void dw_split_kernel(
    const float* __restrict__ xin,
    const int* __restrict__ sidx,
    const float* __restrict__ wd,
    _Float16* __restrict__ a0o,
    _Float16* __restrict__ a1o,
    int Vout, int Cin) {
  const int lpr    = Cin >> 3;
  const int lshift = 31 - __clz(lpr);
  const int rpb    = 256 >> lshift;
  const int lr = threadIdx.x >> lshift;
  const int lc = threadIdx.x & (lpr - 1);
  const int b  = blockIdx.x & 7;
  const int n  = (blockIdx.x >> 3) * rpb + lr;
  const int c8 = lc << 3;
  const float* xb = xin + (size_t)b * Vout * Cin + c8;

  int idx[9];
  #pragma unroll
  for (int s = 0; s < 9; ++s) idx[s] = sidx[n * 9 + s];

  float4 a0 = make_float4(0.f, 0.f, 0.f, 0.f);
  float4 a1 = make_float4(0.f, 0.f, 0.f, 0.f);
  #pragma unroll
  for (int s = 0; s < 9; ++s) {
    const float* xr = xb + (size_t)idx[s] * Cin;
    float4 x0 = *(const float4*)xr;
    float4 x1 = *(const float4*)(xr + 4);
    const float* wr = wd + s * Cin + c8;
    float4 w0 = *(const float4*)wr;
    float4 w1 = *(const float4*)(wr + 4);
    a0.x = fmaf(w0.x, x0.x, a0.x); a0.y = fmaf(w0.y, x0.y, a0.y);
    a0.z = fmaf(w0.z, x0.z, a0.z); a0.w = fmaf(w0.w, x0.w, a0.w);
    a1.x = fmaf(w1.x, x1.x, a1.x); a1.y = fmaf(w1.y, x1.y, a1.y);
    a1.z = fmaf(w1.z, x1.z, a1.z); a1.w = fmaf(w1.w, x1.w, a1.w);
  }

  size_t m = (size_t)b * Vout + n;
  float v[8] = {a0.x, a0.y, a0.z, a0.w, a1.x, a1.y, a1.z, a1.w};
  f16x8 hi, lo;
  #pragma unroll
  for (int i = 0; i < 8; ++i) {
    _Float16 h0 = (_Float16)v[i];
    float r = (v[i] - (float)h0) * 2048.0f;   // exact pow2; lo-plane stays normal
    hi[i] = h0;
    lo[i] = (_Float16)r;
  }
  *(f16x8*)&a0o[m * Cin + c8] = hi;
  *(f16x8*)&a1o[m * Cin + c8] = lo;
}

// ---------------------------------------------------------------- B split, all 4 stages in one launch
struct BsplitParams {
  const float* wp[4];
  int K[4], N[4], off[4];
  _Float16* b0;
  _Float16* b1;
};

__global__ void bsplit_all_kernel(BsplitParams p) {
  int idx = blockIdx.x * 256 + threadIdx.x;
  #pragma unroll
  for (int t = 0; t < 4; ++t) {
    int sz = p.N[t] * p.K[t];
    if (idx < sz) {
      int n = idx / p.K[t], k = idx - n * p.K[t];
      float v = p.wp[t][(size_t)k * p.N[t] + n];
      _Float16 h0 = (_Float16)v;
      float r = (v - (float)h0) * 2048.0f;
      p.b0[p.off[t] + idx] = h0;
      p.b1[p.off[t] + idx] = (_Float16)r;
      return;
    }
    idx -= sz;
  }
}

// ---------------------------------------------------------------- f16x2-split MFMA GEMM + bias + relu (batch-affine)
// BM=128, BN=64, BK=64; 2x2 waves, wave tile 64x32, mfma 16x16x32.
__global__ __launch_bounds__(256) void gemm_f16x2(
    const _Float16* __restrict__ A0, const _Float16* __restrict__ A1,
    const _Float16* __restrict__ Bt0, const _Float16* __restrict__ Bt1,
    const float* __restrict__ bias, float* __restrict__ C,
    int M, int N, int K) {
  constexpr int RP = 72;
  __shared__ _Float16 As[2][128][RP];
  __shared__ _Float16 Bs[2][64][RP];
  const int tid = threadIdx.x;
  const int bx = blockIdx.x;
  const int xr_ = (bx & 7) * (gridDim.x >> 3) + (bx >> 3);   // batch-affine remap
  const int m0 = xr_ * 128, n0 = blockIdx.y * 64;
  const int wid = tid >> 6, lane = tid & 63;
  const int wr = wid >> 1, wc = wid & 1;
  const int lo = lane & 15, hi = lane >> 4;

  f32x4 accM[4][2], accC[4][2];
  #pragma unroll
  for (int mi = 0; mi < 4; ++mi)
    #pragma unroll
    for (int nj = 0; nj < 2; ++nj) {
      accM[mi][nj] = (f32x4){0.f, 0.f, 0.f, 0.f};
      accC[mi][nj] = (f32x4){0.f, 0.f, 0.f, 0.f};
    }

  const _Float16* gA[2] = {A0, A1};
  const _Float16* gB[2] = {Bt0, Bt1};

  for (int k0 = 0; k0 < K; k0 += 64) {
    #pragma unroll
    for (int p = 0; p < 2; ++p) {
      #pragma unroll
      for (int i = 0; i < 4; ++i) {
        int c = tid + 256 * i;
        int r = c >> 3, k8 = (c & 7) << 3;
        uint4 v = *(const uint4*)(gA[p] + (size_t)(m0 + r) * K + k0 + k8);
        *(uint4*)&As[p][r][k8] = v;
      }
      #pragma unroll
      for (int i = 0; i < 2; ++i) {
        int c = tid + 256 * i;
        int r = c >> 3, k8 = (c & 7) << 3;
        uint4 v = *(const uint4*)(gB[p] + (size_t)(n0 + r) * K + k0 + k8);
        *(uint4*)&Bs[p][r][k8] = v;
      }
    }
    __syncthreads();
    #pragma unroll
    for (int s = 0; s < 2; ++s) {
      const int kk = s * 32 + hi * 8;
      f16x8 af[4][2], bf[2][2];
      #pragma unroll
      for (int mi = 0; mi < 4; ++mi) {
        af[mi][0] = *(const f16x8*)&As[0][wr * 64 + mi * 16 + lo][kk];
        af[mi][1] = *(const f16x8*)&As[1][wr * 64 + mi * 16 + lo][kk];
      }
      #pragma unroll
      for (int nj = 0; nj < 2; ++nj) {
        bf[nj][0] = *(const f16x8*)&Bs[0][wc * 32 + nj * 16 + lo][kk];
        bf[nj][1] = *(const f16x8*)&Bs[1][wc * 32 + nj * 16 + lo][kk];
      }
      #pragma unroll
      for (int mi = 0; mi < 4; ++mi)
        #pragma unroll
        for (int nj = 0; nj < 2; ++nj) {
          accM[mi][nj] = __builtin_amdgcn_mfma_f32_16x16x32_f16(
              af[mi][0], bf[nj][0], accM[mi][nj], 0, 0, 0);
          accC[mi][nj] = __builtin_amdgcn_mfma_f32_16x16x32_f16(
              af[mi][0], bf[nj][1], accC[mi][nj], 0, 0, 0);
          accC[mi][nj] = __builtin_amdgcn_mfma_f32_16x16x32_f16(
              af[mi][1], bf[nj][0], accC[mi][nj], 0, 0, 0);
        }
    }
    __syncthreads();
  }

  const float INV = 1.0f / 2048.0f;
  #pragma unroll
  for (int mi = 0; mi < 4; ++mi)
    #pragma unroll
    for (int nj = 0; nj < 2; ++nj) {
      int col = n0 + wc * 32 + nj * 16 + lo;
      float bv = bias[col];
      #pragma unroll
      for (int r = 0; r < 4; ++r) {
        int row = m0 + wr * 64 + mi * 16 + hi * 4 + r;
        float v = accM[mi][nj][r] + accC[mi][nj][r] * INV + bv;
        v = fmaxf(v, 0.f);
        C[(size_t)row * N + col] = v;
      }
    }
}

// ---------------------------------------------------------------- fused head: dw (Cin=64, lane=channel) + 64x3 proj
__global__ __launch_bounds__(256) void head_fused_kernel(
    const float* __restrict__ x,      // [8][8192][64]
    const int* __restrict__ sidx,     // [8192][9]
    const float* __restrict__ wdh,    // [9][64]
    const float* __restrict__ wph,    // [64][3]
    const float* __restrict__ bh,
    float* __restrict__ out) {        // [8][8192][3]
  const int bid  = blockIdx.x;
  const int b    = bid & 7;           // XCD-affine batch
  const int wid  = threadIdx.x >> 6;
  const int lane = threadIdx.x & 63;
  const int n    = (bid >> 3) * 4 + wid;
  const float* xb = x + (size_t)b * 8192 * 64 + lane;

  int idx[9];
  #pragma unroll
  for (int s = 0; s < 9; ++s) idx[s] = sidx[n * 9 + s];

  float acc = 0.f;
  #pragma unroll
  for (int s = 0; s < 9; ++s)
    acc = fmaf(wdh[s * 64 + lane], xb[(size_t)idx[s] * 64], acc);

  float a0 = acc * wph[lane * 3 + 0];
  float a1 = acc * wph[lane * 3 + 1];
  float a2 = acc * wph[lane * 3 + 2];
  for (int off = 32; off > 0; off >>= 1) {
    a0 += __shfl_down(a0, off);
    a1 += __shfl_down(a1, off);
    a2 += __shfl_down(a2, off);
  }
  if (lane == 0) {
    size_t row = (size_t)b * 8192 + n;
    out[row * 3 + 0] = a0 + bh[0];
    out[row * 3 + 1] = a1 + bh[1];
    out[row * 3 + 2] = a2 + bh[2];
  }
}

// ---------------------------------------------------------------- launch
extern "C" void kernel_launch(void* const* d_in, const int* in_sizes, int n_in,
                              void* d_out, int out_size, void* d_ws, size_t ws_size,
                              hipStream_t stream) {
  const float* uv   = (const float*)d_in[0];
  const float* feat = (const float*)d_in[1];
  const float* up   = (const float*)d_in[2];
  const int* sArr[4] = {(const int*)d_in[3], (const int*)d_in[4],
                        (const int*)d_in[5], (const int*)d_in[6]};

  // workspace layout
  const size_t SLAB = 8ull * 2048 * 512;            // 8,388,608 elements
  float* Wf = (float*)d_ws;
  float* S0 = Wf;                                   // fp32 slab (x / gemm out); live < 4.2M floats
  float* S1 = Wf + SLAB;                            // fp32 slab (pool out)
  _Float16* A0 = (_Float16*)(S1 + SLAB);            // dw hi plane
  _Float16* A1 = A0 + SLAB;                         // dw lo plane
  _Float16* Bt0all = (_Float16*)(S0 + 4500000);     // dead upper part of S0
  _Float16* Bt1all = Bt0all + 434176;
  float* xs = (float*)(A1 + SLAB);                  // B*P*512 floats
  int* ib = (int*)(xs + (size_t)B_ * P_ * 512);

  int Vt[4] = {1024, 2048, 4096, 8192};
  int NZ[4] = {3072, 6144, 12288, 24576};
  int* cnt[4]; int* rp[4]; int* co[4]; float* va[4];
  {
    int* pc = ib;
    for (int t = 0; t < 4; ++t) { cnt[t] = pc; pc += Vt[t]; }          // 15360 ints
    for (int t = 0; t < 4; ++t) { rp[t] = pc; pc += Vt[t] + 1; }
    for (int t = 0; t < 4; ++t) { co[t] = pc; pc += NZ[t]; }
    float* pv = (float*)pc;
    for (int t = 0; t < 4; ++t) { va[t] = pv; pv += NZ[t]; }
  }

  CsrParams cp;
  for (int t = 0; t < 4; ++t) {
    int i = 3 - t;
    cp.row[t] = (const int*)d_in[7 + 3 * i];
    cp.col[t] = (const int*)d_in[8 + 3 * i];
    cp.val[t] = (const float*)d_in[9 + 3 * i];
    cp.cnt[t] = cnt[t]; cp.rowptr[t] = rp[t];
    cp.colsout[t] = co[t]; cp.valsout[t] = va[t];
    cp.nnz[t] = NZ[t]; cp.V[t] = Vt[t];
  }

  // CSR build: zero (plain kernel, not blit) + count + scan + fill
  zero_cnt_kernel<<<60, 256, 0, stream>>>(ib, 15360);
  count_kernel<<<dim3(96, 4), 256, 0, stream>>>(cp);
  scan_kernel<<<4, 256, 0, stream>>>(cp);
  fill_kernel<<<dim3(96, 4), 256, 0, stream>>>(cp);

  sample_kernel<<<B_ * P_, 256, 0, stream>>>(uv, feat, xs);
  upsample_kernel<<<dim3(512, B_), 128, 0, stream>>>(up, xs, S0);

  struct Stg { int Vin, Vout, Cin, Cout; const int* s; const float *wd, *wp, *bias; };
  Stg st[4] = {
    {512, 1024, 512, 512, sArr[3], (const float*)d_in[19], (const float*)d_in[20], (const float*)d_in[21]},
    {1024, 2048, 512, 256, sArr[2], (const float*)d_in[22], (const float*)d_in[23], (const float*)d_in[24]},
    {2048, 4096, 256, 128, sArr[1], (const float*)d_in[25], (const float*)d_in[26], (const float*)d_in[27]},
    {4096, 8192, 128, 64, sArr[0], (const float*)d_in[28], (const float*)d_in[29], (const float*)d_in[30]},
  };

  // all 4 B-splits in one launch
  BsplitParams bp;
  int boff = 0;
  for (int t = 0; t < 4; ++t) {
    bp.wp[t] = st[t].wp;
    bp.K[t] = st[t].Cin; bp.N[t] = st[t].Cout;
    bp.off[t] = boff;
    boff += st[t].Cin * st[t].Cout;           // 434176 total
  }
  bp.b0 = Bt0all; bp.b1 = Bt1all;
  bsplit_all_kernel<<<(boff + 255) / 256, 256, 0, stream>>>(bp);

  for (int t = 0; t < 4; ++t) {
    int rpb = 2048 / st[t].Cin;               // rows/block at 8 ch/thread
    pool_kernel<<<8 * (st[t].Vout / rpb), 256, 0, stream>>>(
        S0, rp[t], co[t], va[t], S1, st[t].Vout, st[t].Vin, st[t].Cin);
    dw_split_kernel<<<8 * (st[t].Vout / rpb), 256, 0, stream>>>(
        S1, st[t].s, st[t].wd, A0, A1, st[t].Vout, st[t].Cin);
    int M = B_ * st[t].Vout;
    gemm_f16x2<<<dim3(M / 128, st[t].Cout / 64), 256, 0, stream>>>(
        A0, A1, Bt0all + bp.off[t], Bt1all + bp.off[t],
        st[t].bias, S0, M, st[t].Cout, st[t].Cin);
  }

  // fused head: dw (K=64) + 64x3 projection, one launch
  head_fused_kernel<<<8 * (8192 / 4), 256, 0, stream>>>(
      S0, sArr[0], (const float*)d_in[31], (const float*)d_in[32],
      (const float*)d_in[33], (float*)d_out);
}

// Round 13
// 271.547 us; speedup vs baseline: 1.9143x; 1.0259x over previous
//
#include <hip/hip_runtime.h>

#define B_  8
#define P_  21
#define H_  32
#define W_  32

typedef float f32x4 __attribute__((ext_vector_type(4)));
typedef _Float16 f16x8 __attribute__((ext_vector_type(8)));

// async global->LDS, 16B per lane; LDS dst must be wave-uniform base (HW adds lane*16)
__device__ __forceinline__ void gload_lds16(const _Float16* g, _Float16* l) {
  __builtin_amdgcn_global_load_lds(
      (const __attribute__((address_space(1))) void*)g,
      (__attribute__((address_space(3))) void*)l, 16, 0, 0);
}

// ---------------------------------------------------------------- CSR build (parallel: zero+count+scan+fill)
struct CsrParams {
  const int*   row[4];
  const int*   col[4];
  const float* val[4];
  int*   cnt[4];
  int*   rowptr[4];
  int*   colsout[4];
  float* valsout[4];
  int    nnz[4];
  int    V[4];
};

__global__ void zero_cnt_kernel(int* p, int n) {
  int i = blockIdx.x * 256 + threadIdx.x;
  if (i < n) p[i] = 0;
}

__global__ void count_kernel(CsrParams p) {
  int l = blockIdx.y;
  int k = blockIdx.x * 256 + threadIdx.x;
  if (k < p.nnz[l]) atomicAdd(&p.cnt[l][p.row[l][k]], 1);
}

__global__ void scan_kernel(CsrParams p) {
  int l = blockIdx.x;
  int V = p.V[l];
  int* cnt = p.cnt[l];
  int* rp  = p.rowptr[l];
  int t = threadIdx.x;
  int chunk = V / 256;            // 4,8,16,32 — exact
  int base = t * chunk;
  int s = 0;
  for (int i = 0; i < chunk; ++i) s += cnt[base + i];
  __shared__ int sm[256];
  sm[t] = s;
  __syncthreads();
  for (int off = 1; off < 256; off <<= 1) {
    int v = (t >= off) ? sm[t - off] : 0;
    __syncthreads();
    sm[t] += v;
    __syncthreads();
  }
  int run = sm[t] - s;            // exclusive prefix
  for (int i = 0; i < chunk; ++i) {
    int c = cnt[base + i];
    rp[base + i]  = run;
    cnt[base + i] = run;          // becomes fill cursor
    run += c;
  }
  if (t == 255) rp[V] = run;
}

__global__ void fill_kernel(CsrParams p) {
  int l = blockIdx.y;
  int k = blockIdx.x * 256 + threadIdx.x;
  if (k < p.nnz[l]) {
    int r = p.row[l][k];
    int pos = atomicAdd(&p.cnt[l][r], 1);
    p.colsout[l][pos] = p.col[l][k];
    p.valsout[l][pos] = p.val[l][k];
  }
}

// ---------------------------------------------------------------- sampling
__global__ void sample_kernel(const float* __restrict__ uv,
                              const float* __restrict__ feat,
                              float* __restrict__ xs) {
  int bp = blockIdx.x;
  int b  = bp / P_;
  float u0 = uv[bp * 2 + 0], u1 = uv[bp * 2 + 1];
  float gx = fminf(fmaxf((u0 - 0.5f) * 2.0f, -1.0f), 1.0f);
  float gy = fminf(fmaxf((u1 - 0.5f) * 2.0f, -1.0f), 1.0f);
  float fx = (gx + 1.0f) * 0.5f * (W_ - 1);
  float fy = (gy + 1.0f) * 0.5f * (H_ - 1);
  float x0f = floorf(fx), y0f = floorf(fy);
  float wx = fx - x0f, wy = fy - y0f;
  int x0 = (int)x0f, y0 = (int)y0f;
  int x0i = min(max(x0, 0), W_ - 1), x1i = min(max(x0 + 1, 0), W_ - 1);
  int y0i = min(max(y0, 0), H_ - 1), y1i = min(max(y0 + 1, 0), H_ - 1);
  float w00 = (1.f - wy) * (1.f - wx), w01 = (1.f - wy) * wx;
  float w10 = wy * (1.f - wx),        w11 = wy * wx;
  for (int c = threadIdx.x; c < 512; c += blockDim.x) {
    const float* fb = feat + ((size_t)(b * 512 + c)) * (H_ * W_);
    float v = fb[y0i * W_ + x0i] * w00 + fb[y0i * W_ + x1i] * w01 +
              fb[y1i * W_ + x0i] * w10 + fb[y1i * W_ + x1i] * w11;
    xs[(size_t)bp * 512 + c] = v;
  }
}

__global__ void upsample_kernel(const float* __restrict__ up,
                                const float* __restrict__ xs,
                                float* __restrict__ xu) {
  int v = blockIdx.x, b = blockIdx.y;
  int c4 = threadIdx.x << 2;
  float4 acc = make_float4(0.f, 0.f, 0.f, 0.f);
  for (int p = 0; p < P_; ++p) {
    float u = up[v * P_ + p];
    const float4 xv = *(const float4*)&xs[((size_t)(b * P_ + p)) * 512 + c4];
    acc.x = fmaf(u, xv.x, acc.x);
    acc.y = fmaf(u, xv.y, acc.y);
    acc.z = fmaf(u, xv.z, acc.z);
    acc.w = fmaf(u, xv.w, acc.w);
  }
  *(float4*)&xu[((size_t)(b * 512 + v)) * 512 + c4] = acc;
}

// ---------------------------------------------------------------- pool (CSR gather, batch-affine, 8ch/thread)
__global__ __launch_bounds__(256) void pool_kernel(
    const float* __restrict__ x,
    const int* __restrict__ rowptr,
    const int* __restrict__ cols,
    const float* __restrict__ vals,
    float* __restrict__ out,
    int Vout, int Vin, int Cin) {
  const int lpr    = Cin >> 3;
  const int lshift = 31 - __clz(lpr);
  const int rpb    = 256 >> lshift;
  const int lr = threadIdx.x >> lshift;
  const int lc = threadIdx.x & (lpr - 1);
  const int b  = blockIdx.x & 7;            // XCD-affine batch
  const int n  = (blockIdx.x >> 3) * rpb + lr;
  const int c8 = lc << 3;
  const float* xb = x + (size_t)b * Vin * Cin + c8;
  int j0 = rowptr[n], j1 = rowptr[n + 1];
  int cnt = j1 - j0;
  float4 a0 = make_float4(0.f, 0.f, 0.f, 0.f);
  float4 a1 = make_float4(0.f, 0.f, 0.f, 0.f);
  if (cnt > 0) {
    int   cc[4];
    float vv[4];
    #pragma unroll
    for (int k = 0; k < 4; ++k) {
      int jj = j0 + ((k < cnt) ? k : 0);    // in-bounds (cnt>0)
      cc[k] = cols[jj];
      vv[k] = (k < cnt) ? vals[jj] : 0.f;
    }
    #pragma unroll
    for (int k = 0; k < 4; ++k) {
      const float* xr = xb + (size_t)cc[k] * Cin;
      float4 x0 = *(const float4*)xr;
      float4 x1 = *(const float4*)(xr + 4);
      float v = vv[k];
      a0.x = fmaf(v, x0.x, a0.x); a0.y = fmaf(v, x0.y, a0.y);
      a0.z = fmaf(v, x0.z, a0.z); a0.w = fmaf(v, x0.w, a0.w);
      a1.x = fmaf(v, x1.x, a1.x); a1.y = fmaf(v, x1.y, a1.y);
      a1.z = fmaf(v, x1.z, a1.z); a1.w = fmaf(v, x1.w, a1.w);
    }
    for (int j = j0 + 4; j < j1; ++j) {     // rare tail (cnt>4)
      float v = vals[j];
      const float* xr = xb + (size_t)cols[j] * Cin;
      float4 x0 = *(const float4*)xr;
      float4 x1 = *(const float4*)(xr + 4);
      a0.x = fmaf(v, x0.x, a0.x); a0.y = fmaf(v, x0.y, a0.y);
      a0.z = fmaf(v, x0.z, a0.z); a0.w = fmaf(v, x0.w, a0.w);
      a1.x = fmaf(v, x1.x, a1.x); a1.y = fmaf(v, x1.y, a1.y);
      a1.z = fmaf(v, x1.z, a1.z); a1.w = fmaf(v, x1.w, a1.w);
    }
  }
  float* op = &out[((size_t)b * Vout + n) * Cin + c8];
  *(float4*)op = a0;
  *(float4*)(op + 4) = a1;
}

// ---------------------------------------------------------------- dw gather + f16x2 split (batch-affine, 8ch/thread)
// Output A planes stored PRE-SWIZZLED: 16B chunk c of row m lands at c^(m&7)
// (XOR of low 3 chunk bits) so the GEMM can global_load_lds linearly and
// ds_read with the same XOR (conflict-free). Pure layout permutation.
__global__ __launch_bounds__(256) void dw_split_kernel(
    const float* __restrict__ xin,
    const int* __restrict__ sidx,
    const float* __restrict__ wd,
    _Float16* __restrict__ a0o,
    _Float16* __restrict__ a1o,
    int Vout, int Cin) {
  const int lpr    = Cin >> 3;
  const int lshift = 31 - __clz(lpr);
  const int rpb    = 256 >> lshift;
  const int lr = threadIdx.x >> lshift;
  const int lc = threadIdx.x & (lpr - 1);
  const int b  = blockIdx.x & 7;
  const int n  = (blockIdx.x >> 3) * rpb + lr;
  const int c8 = lc << 3;
  const float* xb = xin + (size_t)b * Vout * Cin + c8;

  int idx[9];
  #pragma unroll
  for (int s = 0; s < 9; ++s) idx[s] = sidx[n * 9 + s];

  float4 a0 = make_float4(0.f, 0.f, 0.f, 0.f);
  float4 a1 = make_float4(0.f, 0.f, 0.f, 0.f);
  #pragma unroll
  for (int s = 0; s < 9; ++s) {
    const float* xr = xb + (size_t)idx[s] * Cin;
    float4 x0 = *(const float4*)xr;
    float4 x1 = *(const float4*)(xr + 4);
    const float* wr = wd + s * Cin + c8;
    float4 w0 = *(const float4*)wr;
    float4 w1 = *(const float4*)(wr + 4);
    a0.x = fmaf(w0.x, x0.x, a0.x); a0.y = fmaf(w0.y, x0.y, a0.y);
    a0.z = fmaf(w0.z, x0.z, a0.z); a0.w = fmaf(w0.w, x0.w, a0.w);
    a1.x = fmaf(w1.x, x1.x, a1.x); a1.y = fmaf(w1.y, x1.y, a1.y);
    a1.z = fmaf(w1.z, x1.z, a1.z); a1.w = fmaf(w1.w, x1.w, a1.w);
  }

  size_t m = (size_t)b * Vout + n;
  float v[8] = {a0.x, a0.y, a0.z, a0.w, a1.x, a1.y, a1.z, a1.w};
  f16x8 hi, lo;
  #pragma unroll
  for (int i = 0; i < 8; ++i) {
    _Float16 h0 = (_Float16)v[i];
    float r = (v[i] - (float)h0) * 2048.0f;   // exact pow2; lo-plane stays normal
    hi[i] = h0;
    lo[i] = (_Float16)r;
  }
  const int c8s = (lc ^ (n & 7)) << 3;        // swizzled chunk position
  *(f16x8*)&a0o[m * Cin + c8s] = hi;
  *(f16x8*)&a1o[m * Cin + c8s] = lo;
}

// ---------------------------------------------------------------- B split, all 4 stages in one launch (pre-swizzled)
struct BsplitParams {
  const float* wp[4];
  int K[4], N[4], off[4];
  _Float16* b0;
  _Float16* b1;
};

__global__ void bsplit_all_kernel(BsplitParams p) {
  int idx = blockIdx.x * 256 + threadIdx.x;
  #pragma unroll
  for (int t = 0; t < 4; ++t) {
    int sz = p.N[t] * p.K[t];
    if (idx < sz) {
      int K = p.K[t];
      int n = idx / K, k = idx - n * K;
      float v = p.wp[t][(size_t)k * p.N[t] + n];
      _Float16 h0 = (_Float16)v;
      float r = (v - (float)h0) * 2048.0f;
      int ks = ((((k >> 3) ^ (n & 7)) << 3) | (k & 7));   // chunk-XOR swizzle
      p.b0[p.off[t] + (size_t)n * K + ks] = h0;
      p.b1[p.off[t] + (size_t)n * K + ks] = (_Float16)r;
      return;
    }
    idx -= sz;
  }
}

// ---------------------------------------------------------------- f16x2-split MFMA GEMM + bias + relu (batch-affine)
// BM=128, BN=64, BK=64; 2x2 waves, wave tile 64x32, mfma 16x16x32.
// Staging via global_load_lds (16B/lane, linear LDS); operands pre-swizzled
// in global (chunk^(row&7)), reads apply the same XOR. LDS 48KB -> 3 blk/CU.
__global__ __launch_bounds__(256) void gemm_f16x2(
    const _Float16* __restrict__ A0, const _Float16* __restrict__ A1,
    const _Float16* __restrict__ Bt0, const _Float16* __restrict__ Bt1,
    const float* __restrict__ bias, float* __restrict__ C,
    int M, int N, int K) {
  __shared__ _Float16 As[2][128 * 64];      // linear; halves index = chunk*8
  __shared__ _Float16 Bs[2][64 * 64];
  const int tid = threadIdx.x;
  const int bx = blockIdx.x;
  const int xr_ = (bx & 7) * (gridDim.x >> 3) + (bx >> 3);   // batch-affine remap
  const int m0 = xr_ * 128, n0 = blockIdx.y * 64;
  const int wid = tid >> 6, lane = tid & 63;
  const int wr = wid >> 1, wc = wid & 1;
  const int lo = lane & 15, hi = lane >> 4;

  f32x4 accM[4][2], accC[4][2];
  #pragma unroll
  for (int mi = 0; mi < 4; ++mi)
    #pragma unroll
    for (int nj = 0; nj < 2; ++nj) {
      accM[mi][nj] = (f32x4){0.f, 0.f, 0.f, 0.f};
      accC[mi][nj] = (f32x4){0.f, 0.f, 0.f, 0.f};
    }

  const _Float16* gA[2] = {A0, A1};
  const _Float16* gB[2] = {Bt0, Bt1};

  for (int k0 = 0; k0 < K; k0 += 64) {
    #pragma unroll
    for (int p = 0; p < 2; ++p) {
      #pragma unroll
      for (int i = 0; i < 4; ++i) {          // A plane: 1024 16B chunks
        int c = tid + 256 * i;
        int r = c >> 3, k8 = (c & 7) << 3;
        gload_lds16(gA[p] + (size_t)(m0 + r) * K + k0 + k8,
                    &As[p][(c & ~63) * 8]);  // wave-uniform base; HW adds lane*16B
      }
      #pragma unroll
      for (int i = 0; i < 2; ++i) {          // B plane: 512 chunks
        int c = tid + 256 * i;
        int r = c >> 3, k8 = (c & 7) << 3;
        gload_lds16(gB[p] + (size_t)(n0 + r) * K + k0 + k8,
                    &Bs[p][(c & ~63) * 8]);
      }
    }
    __syncthreads();                          // compiler drains vmcnt before barrier
    #pragma unroll
    for (int s = 0; s < 2; ++s) {
      const int cl = s * 4 + hi;              // local chunk 0..7 (kk = cl*8)
      f16x8 af[4][2], bf[2][2];
      #pragma unroll
      for (int mi = 0; mi < 4; ++mi) {
        const int rr = wr * 64 + mi * 16 + lo;
        const int ko = (cl ^ (rr & 7)) << 3;  // un-swizzle on read
        af[mi][0] = *(const f16x8*)&As[0][rr * 64 + ko];
        af[mi][1] = *(const f16x8*)&As[1][rr * 64 + ko];
      }
      #pragma unroll
      for (int nj = 0; nj < 2; ++nj) {
        const int rb = wc * 32 + nj * 16 + lo;
        const int ko = (cl ^ (rb & 7)) << 3;
        bf[nj][0] = *(const f16x8*)&Bs[0][rb * 64 + ko];
        bf[nj][1] = *(const f16x8*)&Bs[1][rb * 64 + ko];
      }
      #pragma unroll
      for (int mi = 0; mi < 4; ++mi)
        #pragma unroll
        for (int nj = 0; nj < 2; ++nj) {
          accM[mi][nj] = __builtin_amdgcn_mfma_f32_16x16x32_f16(
              af[mi][0], bf[nj][0], accM[mi][nj], 0, 0, 0);
          accC[mi][nj] = __builtin_amdgcn_mfma_f32_16x16x32_f16(
              af[mi][0], bf[nj][1], accC[mi][nj], 0, 0, 0);
          accC[mi][nj] = __builtin_amdgcn_mfma_f32_16x16x32_f16(
              af[mi][1], bf[nj][0], accC[mi][nj], 0, 0, 0);
        }
    }
    __syncthreads();
  }

  const float INV = 1.0f / 2048.0f;
  #pragma unroll
  for (int mi = 0; mi < 4; ++mi)
    #pragma unroll
    for (int nj = 0; nj < 2; ++nj) {
      int col = n0 + wc * 32 + nj * 16 + lo;
      float bv = bias[col];
      #pragma unroll
      for (int r = 0; r < 4; ++r) {
        int row = m0 + wr * 64 + mi * 16 + hi * 4 + r;
        float v = accM[mi][nj][r] + accC[mi][nj][r] * INV + bv;
        v = fmaxf(v, 0.f);
        C[(size_t)row * N + col] = v;
      }
    }
}

// ---------------------------------------------------------------- fused head: dw (Cin=64, lane=channel) + 64x3 proj
__global__ __launch_bounds__(256) void head_fused_kernel(
    const float* __restrict__ x,      // [8][8192][64]
    const int* __restrict__ sidx,     // [8192][9]
    const float* __restrict__ wdh,    // [9][64]
    const float* __restrict__ wph,    // [64][3]
    const float* __restrict__ bh,
    float* __restrict__ out) {        // [8][8192][3]
  const int bid  = blockIdx.x;
  const int b    = bid & 7;           // XCD-affine batch
  const int wid  = threadIdx.x >> 6;
  const int lane = threadIdx.x & 63;
  const int n    = (bid >> 3) * 4 + wid;
  const float* xb = x + (size_t)b * 8192 * 64 + lane;

  int idx[9];
  #pragma unroll
  for (int s = 0; s < 9; ++s) idx[s] = sidx[n * 9 + s];

  float acc = 0.f;
  #pragma unroll
  for (int s = 0; s < 9; ++s)
    acc = fmaf(wdh[s * 64 + lane], xb[(size_t)idx[s] * 64], acc);

  float a0 = acc * wph[lane * 3 + 0];
  float a1 = acc * wph[lane * 3 + 1];
  float a2 = acc * wph[lane * 3 + 2];
  for (int off = 32; off > 0; off >>= 1) {
    a0 += __shfl_down(a0, off);
    a1 += __shfl_down(a1, off);
    a2 += __shfl_down(a2, off);
  }
  if (lane == 0) {
    size_t row = (size_t)b * 8192 + n;
    out[row * 3 + 0] = a0 + bh[0];
    out[row * 3 + 1] = a1 + bh[1];
    out[row * 3 + 2] = a2 + bh[2];
  }
}

// ---------------------------------------------------------------- launch
extern "C" void kernel_launch(void* const* d_in, const int* in_sizes, int n_in,
                              void* d_out, int out_size, void* d_ws, size_t ws_size,
                              hipStream_t stream) {
  const float* uv   = (const float*)d_in[0];
  const float* feat = (const float*)d_in[1];
  const float* up   = (const float*)d_in[2];
  const int* sArr[4] = {(const int*)d_in[3], (const int*)d_in[4],
                        (const int*)d_in[5], (const int*)d_in[6]};

  // workspace layout
  const size_t SLAB = 8ull * 2048 * 512;            // 8,388,608 elements
  float* Wf = (float*)d_ws;
  float* S0 = Wf;                                   // fp32 slab (x / gemm out); live < 4.2M floats
  float* S1 = Wf + SLAB;                            // fp32 slab (pool out)
  _Float16* A0 = (_Float16*)(S1 + SLAB);            // dw hi plane (pre-swizzled)
  _Float16* A1 = A0 + SLAB;                         // dw lo plane
  _Float16* Bt0all = (_Float16*)(S0 + 4500000);     // dead upper part of S0
  _Float16* Bt1all = Bt0all + 434176;
  float* xs = (float*)(A1 + SLAB);                  // B*P*512 floats
  int* ib = (int*)(xs + (size_t)B_ * P_ * 512);

  int Vt[4] = {1024, 2048, 4096, 8192};
  int NZ[4] = {3072, 6144, 12288, 24576};
  int* cnt[4]; int* rp[4]; int* co[4]; float* va[4];
  {
    int* pc = ib;
    for (int t = 0; t < 4; ++t) { cnt[t] = pc; pc += Vt[t]; }          // 15360 ints
    for (int t = 0; t < 4; ++t) { rp[t] = pc; pc += Vt[t] + 1; }
    for (int t = 0; t < 4; ++t) { co[t] = pc; pc += NZ[t]; }
    float* pv = (float*)pc;
    for (int t = 0; t < 4; ++t) { va[t] = pv; pv += NZ[t]; }
  }

  CsrParams cp;
  for (int t = 0; t < 4; ++t) {
    int i = 3 - t;
    cp.row[t] = (const int*)d_in[7 + 3 * i];
    cp.col[t] = (const int*)d_in[8 + 3 * i];
    cp.val[t] = (const float*)d_in[9 + 3 * i];
    cp.cnt[t] = cnt[t]; cp.rowptr[t] = rp[t];
    cp.colsout[t] = co[t]; cp.valsout[t] = va[t];
    cp.nnz[t] = NZ[t]; cp.V[t] = Vt[t];
  }

  // CSR build: zero (plain kernel, not blit) + count + scan + fill
  zero_cnt_kernel<<<60, 256, 0, stream>>>(ib, 15360);
  count_kernel<<<dim3(96, 4), 256, 0, stream>>>(cp);
  scan_kernel<<<4, 256, 0, stream>>>(cp);
  fill_kernel<<<dim3(96, 4), 256, 0, stream>>>(cp);

  sample_kernel<<<B_ * P_, 256, 0, stream>>>(uv, feat, xs);
  upsample_kernel<<<dim3(512, B_), 128, 0, stream>>>(up, xs, S0);

  struct Stg { int Vin, Vout, Cin, Cout; const int* s; const float *wd, *wp, *bias; };
  Stg st[4] = {
    {512, 1024, 512, 512, sArr[3], (const float*)d_in[19], (const float*)d_in[20], (const float*)d_in[21]},
    {1024, 2048, 512, 256, sArr[2], (const float*)d_in[22], (const float*)d_in[23], (const float*)d_in[24]},
    {2048, 4096, 256, 128, sArr[1], (const float*)d_in[25], (const float*)d_in[26], (const float*)d_in[27]},
    {4096, 8192, 128, 64, sArr[0], (const float*)d_in[28], (const float*)d_in[29], (const float*)d_in[30]},
  };

  // all 4 B-splits in one launch
  BsplitParams bp;
  int boff = 0;
  for (int t = 0; t < 4; ++t) {
    bp.wp[t] = st[t].wp;
    bp.K[t] = st[t].Cin; bp.N[t] = st[t].Cout;
    bp.off[t] = boff;
    boff += st[t].Cin * st[t].Cout;           // 434176 total
  }
  bp.b0 = Bt0all; bp.b1 = Bt1all;
  bsplit_all_kernel<<<(boff + 255) / 256, 256, 0, stream>>>(bp);

  for (int t = 0; t < 4; ++t) {
    int rpb = 2048 / st[t].Cin;               // rows/block at 8 ch/thread
    pool_kernel<<<8 * (st[t].Vout / rpb), 256, 0, stream>>>(
        S0, rp[t], co[t], va[t], S1, st[t].Vout, st[t].Vin, st[t].Cin);
    dw_split_kernel<<<8 * (st[t].Vout / rpb), 256, 0, stream>>>(
        S1, st[t].s, st[t].wd, A0, A1, st[t].Vout, st[t].Cin);
    int M = B_ * st[t].Vout;
    gemm_f16x2<<<dim3(M / 128, st[t].Cout / 64), 256, 0, stream>>>(
        A0, A1, Bt0all + bp.off[t], Bt1all + bp.off[t],
        st[t].bias, S0, M, st[t].Cout, st[t].Cin);
  }

  // fused head: dw (K=64) + 64x3 projection, one launch
  head_fused_kernel<<<8 * (8192 / 4), 256, 0, stream>>>(
      S0, sArr[0], (const float*)d_in[31], (const float*)d_in[32],
      (const float*)d_in[33], (float*)d_out);
}

// Round 14
// 266.649 us; speedup vs baseline: 1.9495x; 1.0184x over previous
//
#include <hip/hip_runtime.h>

#define B_  8
#define P_  21
#define H_  32
#define W_  32

typedef float f32x4 __attribute__((ext_vector_type(4)));
typedef _Float16 f16x8 __attribute__((ext_vector_type(8)));

// async global->LDS, 16B per lane; LDS dst must be wave-uniform base (HW adds lane*16)
__device__ __forceinline__ void gload_lds16(const _Float16* g, _Float16* l) {
  __builtin_amdgcn_global_load_lds(
      (const __attribute__((address_space(1))) void*)g,
      (__attribute__((address_space(3))) void*)l, 16, 0, 0);
}

// ---------------------------------------------------------------- CSR build structs
struct CsrParams {
  const int*   row[4];
  const int*   col[4];
  const float* val[4];
  int*   cnt[4];
  int*   rowptr[4];
  int*   colsout[4];
  float* valsout[4];
  int    nnz[4];
  int    V[4];
};

struct BsplitParams {
  const float* wp[4];
  int K[4], N[4], off[4];
  _Float16* b0;
  _Float16* b1;
};

// ---------------------------------------------------------------- K1: zero (60 blks) || sample (168 blks)
__global__ __launch_bounds__(256) void k1_zero_sample(
    int* zp, int zn,
    const float* __restrict__ uv,
    const float* __restrict__ feat,
    float* __restrict__ xs) {
  int bid = blockIdx.x;
  if (bid < 60) {
    int i = bid * 256 + threadIdx.x;
    if (i < zn) zp[i] = 0;
    return;
  }
  int bp = bid - 60;                 // b*21+p
  int b  = bp / P_;
  float u0 = uv[bp * 2 + 0], u1 = uv[bp * 2 + 1];
  float gx = fminf(fmaxf((u0 - 0.5f) * 2.0f, -1.0f), 1.0f);
  float gy = fminf(fmaxf((u1 - 0.5f) * 2.0f, -1.0f), 1.0f);
  float fx = (gx + 1.0f) * 0.5f * (W_ - 1);
  float fy = (gy + 1.0f) * 0.5f * (H_ - 1);
  float x0f = floorf(fx), y0f = floorf(fy);
  float wx = fx - x0f, wy = fy - y0f;
  int x0 = (int)x0f, y0 = (int)y0f;
  int x0i = min(max(x0, 0), W_ - 1), x1i = min(max(x0 + 1, 0), W_ - 1);
  int y0i = min(max(y0, 0), H_ - 1), y1i = min(max(y0 + 1, 0), H_ - 1);
  float w00 = (1.f - wy) * (1.f - wx), w01 = (1.f - wy) * wx;
  float w10 = wy * (1.f - wx),        w11 = wy * wx;
  for (int c = threadIdx.x; c < 512; c += blockDim.x) {
    const float* fb = feat + ((size_t)(b * 512 + c)) * (H_ * W_);
    float v = fb[y0i * W_ + x0i] * w00 + fb[y0i * W_ + x1i] * w01 +
              fb[y1i * W_ + x0i] * w10 + fb[y1i * W_ + x1i] * w11;
    xs[(size_t)bp * 512 + c] = v;
  }
}

// ---------------------------------------------------------------- K2: count (384 blks) || upsample (4096 blks)
__global__ __launch_bounds__(256) void k2_count_upsample(
    CsrParams p,
    const float* __restrict__ up,
    const float* __restrict__ xs,
    float* __restrict__ xu) {
  int bid = blockIdx.x;
  if (bid < 384) {
    int l = bid / 96;
    int k = (bid - l * 96) * 256 + threadIdx.x;
    if (k < p.nnz[l]) atomicAdd(&p.cnt[l][p.row[l][k]], 1);
    return;
  }
  int b2 = bid - 384;                // [0, 4096)
  int b = b2 >> 9, v = b2 & 511;
  int c2 = threadIdx.x << 1;         // 256 thr * 2 ch = 512
  float2 acc = make_float2(0.f, 0.f);
  for (int q = 0; q < P_; ++q) {
    float u = up[v * P_ + q];
    const float2 xv = *(const float2*)&xs[((size_t)(b * P_ + q)) * 512 + c2];
    acc.x = fmaf(u, xv.x, acc.x);
    acc.y = fmaf(u, xv.y, acc.y);
  }
  *(float2*)&xu[((size_t)(b * 512 + v)) * 512 + c2] = acc;
}

// ---------------------------------------------------------------- K3: scan (4 blks) || bsplit (rest)
__global__ __launch_bounds__(256) void k3_scan_bsplit(CsrParams p, BsplitParams bp) {
  int bid = blockIdx.x;
  if (bid < 4) {
    int l = bid;
    int V = p.V[l];
    int* cnt = p.cnt[l];
    int* rp  = p.rowptr[l];
    int t = threadIdx.x;
    int chunk = V / 256;
    int base = t * chunk;
    int s = 0;
    for (int i = 0; i < chunk; ++i) s += cnt[base + i];
    __shared__ int sm[256];
    sm[t] = s;
    __syncthreads();
    for (int off = 1; off < 256; off <<= 1) {
      int v = (t >= off) ? sm[t - off] : 0;
      __syncthreads();
      sm[t] += v;
      __syncthreads();
    }
    int run = sm[t] - s;
    for (int i = 0; i < chunk; ++i) {
      int c = cnt[base + i];
      rp[base + i]  = run;
      cnt[base + i] = run;
      run += c;
    }
    if (t == 255) rp[V] = run;
    return;
  }
  int idx = (bid - 4) * 256 + threadIdx.x;
  #pragma unroll
  for (int t = 0; t < 4; ++t) {
    int sz = bp.N[t] * bp.K[t];
    if (idx < sz) {
      int K = bp.K[t];
      int n = idx / K, k = idx - n * K;
      float v = bp.wp[t][(size_t)k * bp.N[t] + n];
      _Float16 h0 = (_Float16)v;
      float r = (v - (float)h0) * 2048.0f;
      int ks = ((((k >> 3) ^ (n & 7)) << 3) | (k & 7));   // chunk-XOR swizzle
      bp.b0[bp.off[t] + (size_t)n * K + ks] = h0;
      bp.b1[bp.off[t] + (size_t)n * K + ks] = (_Float16)r;
      return;
    }
    idx -= sz;
  }
}

// ---------------------------------------------------------------- K4: fill
__global__ void fill_kernel(CsrParams p) {
  int l = blockIdx.y;
  int k = blockIdx.x * 256 + threadIdx.x;
  if (k < p.nnz[l]) {
    int r = p.row[l][k];
    int pos = atomicAdd(&p.cnt[l][r], 1);
    p.colsout[l][pos] = p.col[l][k];
    p.valsout[l][pos] = p.val[l][k];
  }
}

// ---------------------------------------------------------------- pool (CSR gather, batch-affine, 8ch/thread)
__global__ __launch_bounds__(256) void pool_kernel(
    const float* __restrict__ x,
    const int* __restrict__ rowptr,
    const int* __restrict__ cols,
    const float* __restrict__ vals,
    float* __restrict__ out,
    int Vout, int Vin, int Cin) {
  const int lpr    = Cin >> 3;
  const int lshift = 31 - __clz(lpr);
  const int rpb    = 256 >> lshift;
  const int lr = threadIdx.x >> lshift;
  const int lc = threadIdx.x & (lpr - 1);
  const int b  = blockIdx.x & 7;            // XCD-affine batch
  const int n  = (blockIdx.x >> 3) * rpb + lr;
  const int c8 = lc << 3;
  const float* xb = x + (size_t)b * Vin * Cin + c8;
  int j0 = rowptr[n], j1 = rowptr[n + 1];
  int cnt = j1 - j0;
  float4 a0 = make_float4(0.f, 0.f, 0.f, 0.f);
  float4 a1 = make_float4(0.f, 0.f, 0.f, 0.f);
  if (cnt > 0) {
    int   cc[4];
    float vv[4];
    #pragma unroll
    for (int k = 0; k < 4; ++k) {
      int jj = j0 + ((k < cnt) ? k : 0);    // in-bounds (cnt>0)
      cc[k] = cols[jj];
      vv[k] = (k < cnt) ? vals[jj] : 0.f;
    }
    #pragma unroll
    for (int k = 0; k < 4; ++k) {
      const float* xr = xb + (size_t)cc[k] * Cin;
      float4 x0 = *(const float4*)xr;
      float4 x1 = *(const float4*)(xr + 4);
      float v = vv[k];
      a0.x = fmaf(v, x0.x, a0.x); a0.y = fmaf(v, x0.y, a0.y);
      a0.z = fmaf(v, x0.z, a0.z); a0.w = fmaf(v, x0.w, a0.w);
      a1.x = fmaf(v, x1.x, a1.x); a1.y = fmaf(v, x1.y, a1.y);
      a1.z = fmaf(v, x1.z, a1.z); a1.w = fmaf(v, x1.w, a1.w);
    }
    for (int j = j0 + 4; j < j1; ++j) {     // rare tail (cnt>4)
      float v = vals[j];
      const float* xr = xb + (size_t)cols[j] * Cin;
      float4 x0 = *(const float4*)xr;
      float4 x1 = *(const float4*)(xr + 4);
      a0.x = fmaf(v, x0.x, a0.x); a0.y = fmaf(v, x0.y, a0.y);
      a0.z = fmaf(v, x0.z, a0.z); a0.w = fmaf(v, x0.w, a0.w);
      a1.x = fmaf(v, x1.x, a1.x); a1.y = fmaf(v, x1.y, a1.y);
      a1.z = fmaf(v, x1.z, a1.z); a1.w = fmaf(v, x1.w, a1.w);
    }
  }
  float* op = &out[((size_t)b * Vout + n) * Cin + c8];
  *(float4*)op = a0;
  *(float4*)(op + 4) = a1;
}

// ---------------------------------------------------------------- dw gather + f16x2 split (batch-affine, 8ch/thread)
// Output A planes PRE-SWIZZLED: chunk c of row m lands at c^(m&7).
__global__ __launch_bounds__(256) void dw_split_kernel(
    const float* __restrict__ xin,
    const int* __restrict__ sidx,
    const float* __restrict__ wd,
    _Float16* __restrict__ a0o,
    _Float16* __restrict__ a1o,
    int Vout, int Cin) {
  const int lpr    = Cin >> 3;
  const int lshift = 31 - __clz(lpr);
  const int rpb    = 256 >> lshift;
  const int lr = threadIdx.x >> lshift;
  const int lc = threadIdx.x & (lpr - 1);
  const int b  = blockIdx.x & 7;
  const int n  = (blockIdx.x >> 3) * rpb + lr;
  const int c8 = lc << 3;
  const float* xb = xin + (size_t)b * Vout * Cin + c8;

  int idx[9];
  #pragma unroll
  for (int s = 0; s < 9; ++s) idx[s] = sidx[n * 9 + s];

  float4 a0 = make_float4(0.f, 0.f, 0.f, 0.f);
  float4 a1 = make_float4(0.f, 0.f, 0.f, 0.f);
  #pragma unroll
  for (int s = 0; s < 9; ++s) {
    const float* xr = xb + (size_t)idx[s] * Cin;
    float4 x0 = *(const float4*)xr;
    float4 x1 = *(const float4*)(xr + 4);
    const float* wr = wd + s * Cin + c8;
    float4 w0 = *(const float4*)wr;
    float4 w1 = *(const float4*)(wr + 4);
    a0.x = fmaf(w0.x, x0.x, a0.x); a0.y = fmaf(w0.y, x0.y, a0.y);
    a0.z = fmaf(w0.z, x0.z, a0.z); a0.w = fmaf(w0.w, x0.w, a0.w);
    a1.x = fmaf(w1.x, x1.x, a1.x); a1.y = fmaf(w1.y, x1.y, a1.y);
    a1.z = fmaf(w1.z, x1.z, a1.z); a1.w = fmaf(w1.w, x1.w, a1.w);
  }

  size_t m = (size_t)b * Vout + n;
  float v[8] = {a0.x, a0.y, a0.z, a0.w, a1.x, a1.y, a1.z, a1.w};
  f16x8 hi, lo;
  #pragma unroll
  for (int i = 0; i < 8; ++i) {
    _Float16 h0 = (_Float16)v[i];
    float r = (v[i] - (float)h0) * 2048.0f;   // exact pow2; lo-plane stays normal
    hi[i] = h0;
    lo[i] = (_Float16)r;
  }
  const int c8s = (lc ^ (n & 7)) << 3;        // swizzled chunk position
  *(f16x8*)&a0o[m * Cin + c8s] = hi;
  *(f16x8*)&a1o[m * Cin + c8s] = lo;
}

// ---------------------------------------------------------------- f16x2-split MFMA GEMM + bias + relu (batch-affine)
// BM=128, BN=64, BK=64; 2x2 waves, wave tile 64x32, mfma 16x16x32.
// Staging via global_load_lds (16B/lane, linear LDS); operands pre-swizzled
// in global (chunk^(row&7)), reads apply the same XOR. LDS 48KB -> 3 blk/CU.
__global__ __launch_bounds__(256) void gemm_f16x2(
    const _Float16* __restrict__ A0, const _Float16* __restrict__ A1,
    const _Float16* __restrict__ Bt0, const _Float16* __restrict__ Bt1,
    const float* __restrict__ bias, float* __restrict__ C,
    int M, int N, int K) {
  __shared__ _Float16 As[2][128 * 64];      // linear; halves index = chunk*8
  __shared__ _Float16 Bs[2][64 * 64];
  const int tid = threadIdx.x;
  const int bx = blockIdx.x;
  const int xr_ = (bx & 7) * (gridDim.x >> 3) + (bx >> 3);   // batch-affine remap
  const int m0 = xr_ * 128, n0 = blockIdx.y * 64;
  const int wid = tid >> 6, lane = tid & 63;
  const int wr = wid >> 1, wc = wid & 1;
  const int lo = lane & 15, hi = lane >> 4;

  f32x4 accM[4][2], accC[4][2];
  #pragma unroll
  for (int mi = 0; mi < 4; ++mi)
    #pragma unroll
    for (int nj = 0; nj < 2; ++nj) {
      accM[mi][nj] = (f32x4){0.f, 0.f, 0.f, 0.f};
      accC[mi][nj] = (f32x4){0.f, 0.f, 0.f, 0.f};
    }

  const _Float16* gA[2] = {A0, A1};
  const _Float16* gB[2] = {Bt0, Bt1};

  for (int k0 = 0; k0 < K; k0 += 64) {
    #pragma unroll
    for (int p = 0; p < 2; ++p) {
      #pragma unroll
      for (int i = 0; i < 4; ++i) {          // A plane: 1024 16B chunks
        int c = tid + 256 * i;
        int r = c >> 3, k8 = (c & 7) << 3;
        gload_lds16(gA[p] + (size_t)(m0 + r) * K + k0 + k8,
                    &As[p][(c & ~63) * 8]);  // wave-uniform base; HW adds lane*16B
      }
      #pragma unroll
      for (int i = 0; i < 2; ++i) {          // B plane: 512 chunks
        int c = tid + 256 * i;
        int r = c >> 3, k8 = (c & 7) << 3;
        gload_lds16(gB[p] + (size_t)(n0 + r) * K + k0 + k8,
                    &Bs[p][(c & ~63) * 8]);
      }
    }
    __syncthreads();                          // compiler drains vmcnt before barrier
    #pragma unroll
    for (int s = 0; s < 2; ++s) {
      const int cl = s * 4 + hi;              // local chunk 0..7 (kk = cl*8)
      f16x8 af[4][2], bf[2][2];
      #pragma unroll
      for (int mi = 0; mi < 4; ++mi) {
        const int rr = wr * 64 + mi * 16 + lo;
        const int ko = (cl ^ (rr & 7)) << 3;  // un-swizzle on read
        af[mi][0] = *(const f16x8*)&As[0][rr * 64 + ko];
        af[mi][1] = *(const f16x8*)&As[1][rr * 64 + ko];
      }
      #pragma unroll
      for (int nj = 0; nj < 2; ++nj) {
        const int rb = wc * 32 + nj * 16 + lo;
        const int ko = (cl ^ (rb & 7)) << 3;
        bf[nj][0] = *(const f16x8*)&Bs[0][rb * 64 + ko];
        bf[nj][1] = *(const f16x8*)&Bs[1][rb * 64 + ko];
      }
      #pragma unroll
      for (int mi = 0; mi < 4; ++mi)
        #pragma unroll
        for (int nj = 0; nj < 2; ++nj) {
          accM[mi][nj] = __builtin_amdgcn_mfma_f32_16x16x32_f16(
              af[mi][0], bf[nj][0], accM[mi][nj], 0, 0, 0);
          accC[mi][nj] = __builtin_amdgcn_mfma_f32_16x16x32_f16(
              af[mi][0], bf[nj][1], accC[mi][nj], 0, 0, 0);
          accC[mi][nj] = __builtin_amdgcn_mfma_f32_16x16x32_f16(
              af[mi][1], bf[nj][0], accC[mi][nj], 0, 0, 0);
        }
    }
    __syncthreads();
  }

  const float INV = 1.0f / 2048.0f;
  #pragma unroll
  for (int mi = 0; mi < 4; ++mi)
    #pragma unroll
    for (int nj = 0; nj < 2; ++nj) {
      int col = n0 + wc * 32 + nj * 16 + lo;
      float bv = bias[col];
      #pragma unroll
      for (int r = 0; r < 4; ++r) {
        int row = m0 + wr * 64 + mi * 16 + hi * 4 + r;
        float v = accM[mi][nj][r] + accC[mi][nj][r] * INV + bv;
        v = fmaxf(v, 0.f);
        C[(size_t)row * N + col] = v;
      }
    }
}

// ---------------------------------------------------------------- fused head: dw (Cin=64, lane=channel) + 64x3 proj
__global__ __launch_bounds__(256) void head_fused_kernel(
    const float* __restrict__ x,      // [8][8192][64]
    const int* __restrict__ sidx,     // [8192][9]
    const float* __restrict__ wdh,    // [9][64]
    const float* __restrict__ wph,    // [64][3]
    const float* __restrict__ bh,
    float* __restrict__ out) {        // [8][8192][3]
  const int bid  = blockIdx.x;
  const int b    = bid & 7;           // XCD-affine batch
  const int wid  = threadIdx.x >> 6;
  const int lane = threadIdx.x & 63;
  const int n    = (bid >> 3) * 4 + wid;
  const float* xb = x + (size_t)b * 8192 * 64 + lane;

  int idx[9];
  #pragma unroll
  for (int s = 0; s < 9; ++s) idx[s] = sidx[n * 9 + s];

  float acc = 0.f;
  #pragma unroll
  for (int s = 0; s < 9; ++s)
    acc = fmaf(wdh[s * 64 + lane], xb[(size_t)idx[s] * 64], acc);

  float a0 = acc * wph[lane * 3 + 0];
  float a1 = acc * wph[lane * 3 + 1];
  float a2 = acc * wph[lane * 3 + 2];
  for (int off = 32; off > 0; off >>= 1) {
    a0 += __shfl_down(a0, off);
    a1 += __shfl_down(a1, off);
    a2 += __shfl_down(a2, off);
  }
  if (lane == 0) {
    size_t row = (size_t)b * 8192 + n;
    out[row * 3 + 0] = a0 + bh[0];
    out[row * 3 + 1] = a1 + bh[1];
    out[row * 3 + 2] = a2 + bh[2];
  }
}

// ---------------------------------------------------------------- launch
extern "C" void kernel_launch(void* const* d_in, const int* in_sizes, int n_in,
                              void* d_out, int out_size, void* d_ws, size_t ws_size,
                              hipStream_t stream) {
  const float* uv   = (const float*)d_in[0];
  const float* feat = (const float*)d_in[1];
  const float* up   = (const float*)d_in[2];
  const int* sArr[4] = {(const int*)d_in[3], (const int*)d_in[4],
                        (const int*)d_in[5], (const int*)d_in[6]};

  // workspace layout
  const size_t SLAB = 8ull * 2048 * 512;            // 8,388,608 elements
  float* Wf = (float*)d_ws;
  float* S0 = Wf;                                   // fp32 slab (x / gemm out); live < 4.2M floats
  float* S1 = Wf + SLAB;                            // fp32 slab (pool out)
  _Float16* A0 = (_Float16*)(S1 + SLAB);            // dw hi plane (pre-swizzled)
  _Float16* A1 = A0 + SLAB;                         // dw lo plane
  _Float16* Bt0all = (_Float16*)(S0 + 4500000);     // dead upper part of S0
  _Float16* Bt1all = Bt0all + 434176;
  float* xs = (float*)(A1 + SLAB);                  // B*P*512 floats
  int* ib = (int*)(xs + (size_t)B_ * P_ * 512);

  int Vt[4] = {1024, 2048, 4096, 8192};
  int NZ[4] = {3072, 6144, 12288, 24576};
  int* cnt[4]; int* rp[4]; int* co[4]; float* va[4];
  {
    int* pc = ib;
    for (int t = 0; t < 4; ++t) { cnt[t] = pc; pc += Vt[t]; }          // 15360 ints
    for (int t = 0; t < 4; ++t) { rp[t] = pc; pc += Vt[t] + 1; }
    for (int t = 0; t < 4; ++t) { co[t] = pc; pc += NZ[t]; }
    float* pv = (float*)pc;
    for (int t = 0; t < 4; ++t) { va[t] = pv; pv += NZ[t]; }
  }

  CsrParams cp;
  for (int t = 0; t < 4; ++t) {
    int i = 3 - t;
    cp.row[t] = (const int*)d_in[7 + 3 * i];
    cp.col[t] = (const int*)d_in[8 + 3 * i];
    cp.val[t] = (const float*)d_in[9 + 3 * i];
    cp.cnt[t] = cnt[t]; cp.rowptr[t] = rp[t];
    cp.colsout[t] = co[t]; cp.valsout[t] = va[t];
    cp.nnz[t] = NZ[t]; cp.V[t] = Vt[t];
  }

  struct Stg { int Vin, Vout, Cin, Cout; const int* s; const float *wd, *wp, *bias; };
  Stg st[4] = {
    {512, 1024, 512, 512, sArr[3], (const float*)d_in[19], (const float*)d_in[20], (const float*)d_in[21]},
    {1024, 2048, 512, 256, sArr[2], (const float*)d_in[22], (const float*)d_in[23], (const float*)d_in[24]},
    {2048, 4096, 256, 128, sArr[1], (const float*)d_in[25], (const float*)d_in[26], (const float*)d_in[27]},
    {4096, 8192, 128, 64, sArr[0], (const float*)d_in[28], (const float*)d_in[29], (const float*)d_in[30]},
  };

  BsplitParams bp;
  int boff = 0;
  for (int t = 0; t < 4; ++t) {
    bp.wp[t] = st[t].wp;
    bp.K[t] = st[t].Cin; bp.N[t] = st[t].Cout;
    bp.off[t] = boff;
    boff += st[t].Cin * st[t].Cout;           // 434176 total
  }
  bp.b0 = Bt0all; bp.b1 = Bt1all;
  int bsplit_blocks = (boff + 255) / 256;     // 1696

  // front matter: 4 merged kernels (3 independent chains interleaved)
  k1_zero_sample<<<60 + B_ * P_, 256, 0, stream>>>(ib, 15360, uv, feat, xs);
  k2_count_upsample<<<384 + 512 * B_, 256, 0, stream>>>(cp, up, xs, S0);
  k3_scan_bsplit<<<4 + bsplit_blocks, 256, 0, stream>>>(cp, bp);
  fill_kernel<<<dim3(96, 4), 256, 0, stream>>>(cp);

  for (int t = 0; t < 4; ++t) {
    int rpb = 2048 / st[t].Cin;               // rows/block at 8 ch/thread
    pool_kernel<<<8 * (st[t].Vout / rpb), 256, 0, stream>>>(
        S0, rp[t], co[t], va[t], S1, st[t].Vout, st[t].Vin, st[t].Cin);
    dw_split_kernel<<<8 * (st[t].Vout / rpb), 256, 0, stream>>>(
        S1, st[t].s, st[t].wd, A0, A1, st[t].Vout, st[t].Cin);
    int M = B_ * st[t].Vout;
    gemm_f16x2<<<dim3(M / 128, st[t].Cout / 64), 256, 0, stream>>>(
        A0, A1, Bt0all + bp.off[t], Bt1all + bp.off[t],
        st[t].bias, S0, M, st[t].Cout, st[t].Cin);
  }

  // fused head: dw (K=64) + 64x3 projection, one launch
  head_fused_kernel<<<8 * (8192 / 4), 256, 0, stream>>>(
      S0, sArr[0], (const float*)d_in[31], (const float*)d_in[32],
      (const float*)d_in[33], (float*)d_out);
}